// Round 9
// baseline (1073.042 us; speedup 1.0000x reference)
//
#include <hip/hip_runtime.h>
#include <cmath>

#define NN 50000
#define CAP 64               // ELL capacity; P(deg > 64 anywhere) ~ 1e-16 for E=800k

typedef short v8s __attribute__((ext_vector_type(8)));   // 8 x bf16 (4 VGPRs)
typedef float v4f __attribute__((ext_vector_type(4)));

__device__ __forceinline__ float b2f(unsigned short u) {
    return __uint_as_float(((unsigned int)u) << 16);
}
__device__ __forceinline__ unsigned short f2b(float f) {
    unsigned int x = __float_as_uint(f);
    x += 0x7fffu + ((x >> 16) & 1u);          // round-to-nearest-even
    return (unsigned short)(x >> 16);
}

// ---- dtype sniffer: mode=0 -> inputs are bf16, mode=1 -> inputs are float32 ----
__global__ void sniff_kernel(const unsigned short* __restrict__ x, int* __restrict__ mode) {
    if (threadIdx.x == 0 && blockIdx.x == 0) {
        int c = 0;
        for (int i = 0; i < 128; ++i) {
            unsigned int e = (x[i] >> 7) & 0xFFu;
            if (e >= 100u && e <= 140u) ++c;
        }
        *mode = (c >= 112) ? 0 : 1;
    }
}

// ---- ELL fill: one atomic pass, no scan ----
__global__ void fill_kernel(const int* __restrict__ src, const int* __restrict__ dst,
                            int* __restrict__ cnt, unsigned short* __restrict__ ell, int E) {
    int e = blockIdx.x * blockDim.x + threadIdx.x;
    if (e < E) {
        int d = dst[e];
        int pos = atomicAdd(&cnt[d], 1);
        if (pos < CAP) ell[d * CAP + pos] = (unsigned short)src[e];
    }
}

// ---- dinv from counts ----
__global__ void dinv_kernel(const int* __restrict__ cnt, float* __restrict__ dinv, int n) {
    int i = blockIdx.x * blockDim.x + threadIdx.x;
    if (i < n) {
        int d = cnt[i];
        dinv[i] = (d > 0) ? rsqrtf((float)d) : 0.0f;
    }
}

// ---- fused prep: pack x into buf cols 0:128 (ld 512), W->WT bf16, biases ----
__global__ void prep_kernel(const void* __restrict__ x,
                            const void* __restrict__ W1, const void* __restrict__ W2,
                            const void* __restrict__ W3, const void* __restrict__ b1,
                            const void* __restrict__ b2, const void* __restrict__ b3,
                            unsigned short* __restrict__ buf,
                            unsigned short* __restrict__ WT1, unsigned short* __restrict__ WT2,
                            unsigned short* __restrict__ WT3, unsigned short* __restrict__ bb1,
                            unsigned short* __restrict__ bb2, unsigned short* __restrict__ bb3,
                            const int* __restrict__ modep) {
    int mode = *modep;
    int b = blockIdx.x, t = threadIdx.x;
    if (b < 3125) {                                   // pack x: NN*16 uint4 chunks
        int idx = b * 256 + t;                        // idx < 800000
        int n = idx >> 4, c = idx & 15;
        if (mode == 0) {
            ((uint4*)buf)[n * 64 + c] = ((const uint4*)x)[idx];
        } else {
            const float* xf = (const float*)x + (size_t)idx * 8;
            unsigned short o[8];
#pragma unroll
            for (int i = 0; i < 8; ++i) o[i] = f2b(xf[i]);
            ((uint4*)buf)[n * 64 + c] = *(const uint4*)o;
        }
    } else if (b < 3381) {                            // WT1 [256][256] from W1[256][256]
        int idx = (b - 3125) * 256 + t;
        int n = idx >> 8, k = idx & 255;
        WT1[idx] = mode ? f2b(((const float*)W1)[k * 256 + n])
                        : ((const unsigned short*)W1)[k * 256 + n];
    } else if (b < 3893) {                            // WT2 [256][512] from W2[512][256]
        int idx = (b - 3381) * 256 + t;
        int n = idx >> 9, k = idx & 511;
        WT2[idx] = mode ? f2b(((const float*)W2)[k * 256 + n])
                        : ((const unsigned short*)W2)[k * 256 + n];
    } else if (b < 4149) {                            // WT3 [128][512] from W3[512][128]
        int idx = (b - 3893) * 256 + t;
        int n = idx >> 9, k = idx & 511;
        WT3[idx] = mode ? f2b(((const float*)W3)[k * 128 + n])
                        : ((const unsigned short*)W3)[k * 128 + n];
    } else {                                          // biases
        if (t < 256) {
            bb1[t] = mode ? f2b(((const float*)b1)[t]) : ((const unsigned short*)b1)[t];
            bb2[t] = mode ? f2b(((const float*)b2)[t]) : ((const unsigned short*)b2)[t];
        }
        if (t < 128)
            bb3[t] = mode ? f2b(((const float*)b3)[t]) : ((const unsigned short*)b3)[t];
    }
}

// ---- XCD-sliced SpMM: wave = (node, 32-col slice). slice = blockIdx % NS so each
// XCD (round-robin on blockIdx) keeps ONE slice (50000*64B = 3.2MB) L2-resident.
// lane: e = lane>>4 (edge sub-index, 4/instr), cp = lane&15 (ushort2 col pair).
// Cross-e reduction via shfl_xor(16,32). h is buf (ld 512); out col OBASE+slice*32.
template <int NS, int OBASE>
__global__ void spmm_kernel(const unsigned short* __restrict__ h,
                            const int* __restrict__ cnt,
                            const unsigned short* __restrict__ ell,
                            const float* __restrict__ dinv,
                            unsigned short* __restrict__ out) {
    const int s = blockIdx.x % NS;
    const int node = (blockIdx.x / NS) * 4 + (threadIdx.x >> 6);
    const int lane = threadIdx.x & 63;
    const int e = lane >> 4, cp = lane & 15;
    int c = cnt[node]; c = (c < CAP) ? c : CAP;
    int sl = 0; float dl = 0.f;
    if (lane < c) { sl = (int)ell[node * CAP + lane]; dl = dinv[sl]; }  // tail lanes: w=0, row 0
    const int colb = s * 32 + cp * 2;
    float a0 = 0.f, a1 = 0.f;
    const int cpad = (c + 7) & ~7;
    for (int g = 0; g < cpad; g += 8) {
        int i0 = g + e, i1 = g + 4 + e;
        int s0 = __shfl(sl, i0), s1 = __shfl(sl, i1);
        float d0 = __shfl(dl, i0), d1 = __shfl(dl, i1);
        ushort2 v0 = *(const ushort2*)(h + (size_t)s0 * 512 + colb);
        ushort2 v1 = *(const ushort2*)(h + (size_t)s1 * 512 + colb);
        a0 += d0 * b2f(v0.x) + d1 * b2f(v1.x);
        a1 += d0 * b2f(v0.y) + d1 * b2f(v1.y);
    }
    a0 += __shfl_xor(a0, 16); a0 += __shfl_xor(a0, 32);
    a1 += __shfl_xor(a1, 16); a1 += __shfl_xor(a1, 32);
    if (lane < 16) {
        float dn = -dinv[node];
        ushort2 o; o.x = f2b(a0 * dn); o.y = f2b(a1 * dn);
        *(ushort2*)(out + (size_t)node * 512 + OBASE + colb) = o;
    }
}

// ---- barrier-free direct-load MFMA GEMM ----
// No LDS: B (WT, <=512KB) is L2-resident; A rows read once. Each wave owns a
// 64x64 tile: 4x4 mfma, fragments loaded straight from global as v8s (64B-line
// aligned gathers), compiler pipelines loads across K (no staging barriers).
// NT=4: block = 4 col-tiles x 64 rows; NT=2: block = 2x2 tiles x 128 rows.
// Block owns its rows; one __syncthreads before epilogue -> in-place safe.
template <int K32, int NT>
__global__ __launch_bounds__(256) void gemm_kernel(
        const unsigned short* __restrict__ A, int lda,
        const unsigned short* __restrict__ WT,    // [NT*64 x K] bf16
        const unsigned short* __restrict__ bias,  // bf16
        void* __restrict__ out, int ldo,
        int M, int dotanh, int is_final, const int* __restrict__ modep) {
    constexpr int K = K32 * 32;
    constexpr int RPB = (4 / NT) * 64;            // rows per block
    const int tid = threadIdx.x;
    const int wave = tid >> 6, lane = tid & 63, quad = lane >> 4, l16 = lane & 15;
    const int mrow = wave / NT, nq = wave % NT;
    const int m0 = blockIdx.x * RPB + mrow * 64;
    const int n0 = nq * 64;

    const unsigned short* Ap[4];
#pragma unroll
    for (int mi = 0; mi < 4; ++mi) {
        int r = m0 + mi * 16 + l16;
        if (r >= M) r = M - 1;                    // clamp only fires in last block (own rows)
        Ap[mi] = A + (size_t)r * lda + quad * 8;
    }
    const unsigned short* Bp[4];
#pragma unroll
    for (int ni = 0; ni < 4; ++ni)
        Bp[ni] = WT + (size_t)(n0 + ni * 16 + l16) * K + quad * 8;

    v4f acc[4][4];
#pragma unroll
    for (int mi = 0; mi < 4; ++mi)
#pragma unroll
        for (int ni = 0; ni < 4; ++ni) acc[mi][ni] = (v4f){0.f, 0.f, 0.f, 0.f};

#pragma unroll 2
    for (int j = 0; j < K32; ++j) {
        v8s a[4], b[4];
#pragma unroll
        for (int mi = 0; mi < 4; ++mi) a[mi] = *(const v8s*)(Ap[mi] + j * 32);
#pragma unroll
        for (int ni = 0; ni < 4; ++ni) b[ni] = *(const v8s*)(Bp[ni] + j * 32);
#pragma unroll
        for (int mi = 0; mi < 4; ++mi)
#pragma unroll
            for (int ni = 0; ni < 4; ++ni)
                acc[mi][ni] = __builtin_amdgcn_mfma_f32_16x16x32_bf16(a[mi], b[ni],
                                                                      acc[mi][ni], 0, 0, 0);
    }

    __syncthreads();   // in-place safety: all A reads in block complete before stores

    int fin = is_final ? *modep : 0;
#pragma unroll
    for (int ni = 0; ni < 4; ++ni) {
        int colc = n0 + ni * 16 + l16;
        float bv = b2f(bias[colc]);
#pragma unroll
        for (int mi = 0; mi < 4; ++mi) {
#pragma unroll
            for (int r = 0; r < 4; ++r) {
                int row = m0 + mi * 16 + quad * 4 + r;
                if (row < M) {
                    float v = acc[mi][ni][r] + bv;
                    if (dotanh) v = tanhf(v);
                    if (fin) ((float*)out)[(size_t)row * ldo + colc] = v;
                    else     ((unsigned short*)out)[(size_t)row * ldo + colc] = f2b(v);
                }
            }
        }
    }
}

static inline size_t al256(size_t x) { return (x + 255) & ~(size_t)255; }

extern "C" void kernel_launch(void* const* d_in, const int* in_sizes, int n_in,
                              void* d_out, int out_size, void* d_ws, size_t ws_size,
                              hipStream_t stream) {
    const void* x  = d_in[0];
    const int* src = (const int*)d_in[1];
    const int* dst = (const int*)d_in[2];
    const void* W1 = d_in[3]; const void* b1 = d_in[4];
    const void* W2 = d_in[5]; const void* b2 = d_in[6];
    const void* W3 = d_in[7]; const void* b3 = d_in[8];
    const int E = in_sizes[1];

    // workspace carve-up (~58.6 MB)
    char* p = (char*)d_ws;
    int* mode     = (int*)p;            p += 256;
    int* cnt      = (int*)p;            p += al256((size_t)NN * 4);
    float* dinv   = (float*)p;          p += al256((size_t)NN * 4);
    unsigned short* ell = (unsigned short*)p; p += al256((size_t)NN * CAP * 2);
    unsigned short* WT1 = (unsigned short*)p; p += al256((size_t)256 * 256 * 2);
    unsigned short* WT2 = (unsigned short*)p; p += al256((size_t)256 * 512 * 2);
    unsigned short* WT3 = (unsigned short*)p; p += al256((size_t)128 * 512 * 2);
    unsigned short* bb1 = (unsigned short*)p; p += al256((size_t)256 * 2);
    unsigned short* bb2 = (unsigned short*)p; p += al256((size_t)256 * 2);
    unsigned short* bb3 = (unsigned short*)p; p += al256((size_t)128 * 2);
    unsigned short* buf = (unsigned short*)p; p += al256((size_t)NN * 512 * 2);

    hipMemsetAsync(cnt, 0, (size_t)NN * 4, stream);
    sniff_kernel<<<1, 64, 0, stream>>>((const unsigned short*)x, mode);
    prep_kernel<<<4150, 256, 0, stream>>>(x, W1, W2, W3, b1, b2, b3,
                                          buf, WT1, WT2, WT3, bb1, bb2, bb3, mode);
    int eb = (E + 255) / 256;
    fill_kernel<<<eb, 256, 0, stream>>>(src, dst, cnt, ell, E);
    dinv_kernel<<<(NN + 255) / 256, 256, 0, stream>>>(cnt, dinv, NN);

    const int SG1 = 4 * (NN / 4);          // L1: 4 slices x 12500 node-groups
    const int SG  = 8 * (NN / 4);          // L2+: 8 slices x 12500
    const int GB4 = (NN + 63) / 64;        // 782 blocks (NT=4)
    const int GB2 = (NN + 127) / 128;      // 391 blocks (NT=2)

    // L1: buf = [x(0:128) | x1(128:256)]; gemm K=256 in-place -> cols 0:256
    spmm_kernel<4, 128><<<SG1, 256, 0, stream>>>(buf, cnt, ell, dinv, buf);
    gemm_kernel<8, 4><<<GB4, 256, 0, stream>>>(buf, 512, WT1, bb1, buf, 512, NN, 1, 0, mode);
    // L2..L4: x1 into cols 256:512, gemm K=512 in-place -> cols 0:256
    spmm_kernel<8, 256><<<SG, 256, 0, stream>>>(buf, cnt, ell, dinv, buf);
    gemm_kernel<16, 4><<<GB4, 256, 0, stream>>>(buf, 512, WT2, bb2, buf, 512, NN, 1, 0, mode);
    spmm_kernel<8, 256><<<SG, 256, 0, stream>>>(buf, cnt, ell, dinv, buf);
    gemm_kernel<16, 4><<<GB4, 256, 0, stream>>>(buf, 512, WT2, bb2, buf, 512, NN, 1, 0, mode);
    spmm_kernel<8, 256><<<SG, 256, 0, stream>>>(buf, cnt, ell, dinv, buf);
    gemm_kernel<16, 4><<<GB4, 256, 0, stream>>>(buf, 512, WT2, bb2, buf, 512, NN, 1, 0, mode);
    // L5 (no tanh) -> d_out (50000 x 128, bf16 or fp32 per mode)
    spmm_kernel<8, 256><<<SG, 256, 0, stream>>>(buf, cnt, ell, dinv, buf);
    gemm_kernel<16, 2><<<GB2, 256, 0, stream>>>(buf, 512, WT3, bb3, d_out, 128, NN, 0, 1, mode);
}

// Round 10
// 744.426 us; speedup vs baseline: 1.4414x; 1.4414x over previous
//
#include <hip/hip_runtime.h>
#include <cmath>

#define NN 50000
#define CAP 64               // ELL capacity; P(deg > 64 anywhere) ~ 1e-16 for E=800k

typedef short v8s __attribute__((ext_vector_type(8)));   // 8 x bf16 (4 VGPRs)
typedef float v4f __attribute__((ext_vector_type(4)));

__device__ __forceinline__ float b2f(unsigned short u) {
    return __uint_as_float(((unsigned int)u) << 16);
}
__device__ __forceinline__ unsigned short f2b(float f) {
    unsigned int x = __float_as_uint(f);
    x += 0x7fffu + ((x >> 16) & 1u);          // round-to-nearest-even
    return (unsigned short)(x >> 16);
}

// ---- dtype sniffer: mode=0 -> inputs are bf16, mode=1 -> inputs are float32 ----
__global__ void sniff_kernel(const unsigned short* __restrict__ x, int* __restrict__ mode) {
    if (threadIdx.x == 0 && blockIdx.x == 0) {
        int c = 0;
        for (int i = 0; i < 128; ++i) {
            unsigned int e = (x[i] >> 7) & 0xFFu;
            if (e >= 100u && e <= 140u) ++c;
        }
        *mode = (c >= 112) ? 0 : 1;
    }
}

// ---- ELL fill: one atomic pass, no scan ----
__global__ void fill_kernel(const int* __restrict__ src, const int* __restrict__ dst,
                            int* __restrict__ cnt, unsigned short* __restrict__ ell, int E) {
    int e = blockIdx.x * blockDim.x + threadIdx.x;
    if (e < E) {
        int d = dst[e];
        int pos = atomicAdd(&cnt[d], 1);
        if (pos < CAP) ell[d * CAP + pos] = (unsigned short)src[e];
    }
}

// ---- dinv from counts ----
__global__ void dinv_kernel(const int* __restrict__ cnt, float* __restrict__ dinv, int n) {
    int i = blockIdx.x * blockDim.x + threadIdx.x;
    if (i < n) {
        int d = cnt[i];
        dinv[i] = (d > 0) ? rsqrtf((float)d) : 0.0f;
    }
}

// ---- fused prep: pack x into buf cols 0:128 (ld 512), W->WT bf16, biases ----
__global__ void prep_kernel(const void* __restrict__ x,
                            const void* __restrict__ W1, const void* __restrict__ W2,
                            const void* __restrict__ W3, const void* __restrict__ b1,
                            const void* __restrict__ b2, const void* __restrict__ b3,
                            unsigned short* __restrict__ buf,
                            unsigned short* __restrict__ WT1, unsigned short* __restrict__ WT2,
                            unsigned short* __restrict__ WT3, unsigned short* __restrict__ bb1,
                            unsigned short* __restrict__ bb2, unsigned short* __restrict__ bb3,
                            const int* __restrict__ modep) {
    int mode = *modep;
    int b = blockIdx.x, t = threadIdx.x;
    if (b < 3125) {                                   // pack x: NN*16 uint4 chunks
        int idx = b * 256 + t;                        // idx < 800000
        int n = idx >> 4, c = idx & 15;
        if (mode == 0) {
            ((uint4*)buf)[n * 64 + c] = ((const uint4*)x)[idx];
        } else {
            const float* xf = (const float*)x + (size_t)idx * 8;
            unsigned short o[8];
#pragma unroll
            for (int i = 0; i < 8; ++i) o[i] = f2b(xf[i]);
            ((uint4*)buf)[n * 64 + c] = *(const uint4*)o;
        }
    } else if (b < 3381) {                            // WT1 [256][256] from W1[256][256]
        int idx = (b - 3125) * 256 + t;
        int n = idx >> 8, k = idx & 255;
        WT1[idx] = mode ? f2b(((const float*)W1)[k * 256 + n])
                        : ((const unsigned short*)W1)[k * 256 + n];
    } else if (b < 3893) {                            // WT2 [256][512] from W2[512][256]
        int idx = (b - 3381) * 256 + t;
        int n = idx >> 9, k = idx & 511;
        WT2[idx] = mode ? f2b(((const float*)W2)[k * 256 + n])
                        : ((const unsigned short*)W2)[k * 256 + n];
    } else if (b < 4149) {                            // WT3 [128][512] from W3[512][128]
        int idx = (b - 3893) * 256 + t;
        int n = idx >> 9, k = idx & 511;
        WT3[idx] = mode ? f2b(((const float*)W3)[k * 128 + n])
                        : ((const unsigned short*)W3)[k * 128 + n];
    } else {                                          // biases
        if (t < 256) {
            bb1[t] = mode ? f2b(((const float*)b1)[t]) : ((const unsigned short*)b1)[t];
            bb2[t] = mode ? f2b(((const float*)b2)[t]) : ((const unsigned short*)b2)[t];
        }
        if (t < 128)
            bb3[t] = mode ? f2b(((const float*)b3)[t]) : ((const unsigned short*)b3)[t];
    }
}

// ---- SpMM (ELL): one wave per dst node (r8-verified, 56us/178MB) ----
template <int FPL>   // features per lane: F = 64*FPL (2 -> 128, 4 -> 256)
__global__ void spmm_kernel(const unsigned short* __restrict__ h, int ldh,
                            const int* __restrict__ cnt, const unsigned short* __restrict__ ell,
                            const float* __restrict__ dinv,
                            unsigned short* __restrict__ out, int ldo) {
    int node = blockIdx.x * 4 + (threadIdx.x >> 6);
    int lane = threadIdx.x & 63;
    int c = cnt[node]; c = (c < CAP) ? c : CAP;
    int sl = (int)ell[node * CAP + lane];      // coalesced; lanes >= c hold junk (unused)
    float dl = dinv[sl];
    float acc[FPL];
#pragma unroll
    for (int i = 0; i < FPL; ++i) acc[i] = 0.f;
    const int col = lane * FPL;

    int g = 0;
    for (; g + 8 <= c; g += 8) {
        int s[8]; float d[8];
#pragma unroll
        for (int i = 0; i < 8; ++i) { s[i] = __shfl(sl, g + i); d[i] = __shfl(dl, g + i); }
        if (FPL == 4) {
            ushort4 v[8];
#pragma unroll
            for (int i = 0; i < 8; ++i)
                v[i] = *(const ushort4*)(h + (size_t)s[i] * ldh + col);
#pragma unroll
            for (int i = 0; i < 8; ++i) {
                acc[0] += d[i] * b2f(v[i].x); acc[1] += d[i] * b2f(v[i].y);
                acc[2] += d[i] * b2f(v[i].z); acc[3] += d[i] * b2f(v[i].w);
            }
        } else {
            ushort2 v[8];
#pragma unroll
            for (int i = 0; i < 8; ++i)
                v[i] = *(const ushort2*)(h + (size_t)s[i] * ldh + col);
#pragma unroll
            for (int i = 0; i < 8; ++i) {
                acc[0] += d[i] * b2f(v[i].x); acc[1] += d[i] * b2f(v[i].y);
            }
        }
    }
    for (; g < c; ++g) {
        int sg = __shfl(sl, g);
        float dg = __shfl(dl, g);
        const unsigned short* hp = h + (size_t)sg * ldh + col;
        if (FPL == 4) {
            ushort4 v = *(const ushort4*)hp;
            acc[0] += dg * b2f(v.x); acc[1] += dg * b2f(v.y);
            acc[2] += dg * b2f(v.z); acc[3] += dg * b2f(v.w);
        } else {
            ushort2 v = *(const ushort2*)hp;
            acc[0] += dg * b2f(v.x); acc[1] += dg * b2f(v.y);
        }
    }

    float dn = -dinv[node];
    unsigned short* op = out + (size_t)node * ldo + col;
    if (FPL == 4) {
        ushort4 o;
        o.x = f2b(acc[0] * dn); o.y = f2b(acc[1] * dn);
        o.z = f2b(acc[2] * dn); o.w = f2b(acc[3] * dn);
        *(ushort4*)op = o;
    } else {
        ushort2 o;
        o.x = f2b(acc[0] * dn); o.y = f2b(acc[1] * dn);
        *(ushort2*)op = o;
    }
}

// ---- GEMM: A staged ONCE in LDS (64 rows x K, row pad +8 -> 2-way bank = free),
// then a BARRIER-FREE K-loop: a_frag via ds_read_b128, b_frag direct from global
// (WT <= 512KB, L2-resident; ~200MB total L2 reads ~ 6us). Avoids r8's 16x
// per-K-step vmcnt(0)+barrier drain AND r9's 4x A re-read from HBM.
// Block = 64 rows x NT*64 cols, NT waves (wave w -> col tile w). In-place safe:
// block stages its own rows before the K-loop; stores only after.
template <int K32, int NT>
__global__ void gemm_kernel(
        const unsigned short* __restrict__ A, int lda,
        const unsigned short* __restrict__ WT,    // [NT*64 x K] bf16
        const unsigned short* __restrict__ bias,  // bf16
        void* __restrict__ out, int ldo,
        int M, int dotanh, int is_final, const int* __restrict__ modep) {
    constexpr int K    = K32 * 32;
    constexpr int LDK  = K + 8;                   // padded LDS row stride (elems)
    constexpr int NTHR = NT * 64;
    constexpr int CPR  = K / 8;                   // 16B chunks per row
    constexpr int ROUNDS = 64 * CPR / NTHR;
    __shared__ unsigned short aT[64 * LDK];

    const int tid = threadIdx.x;
    const int wave = tid >> 6, lane = tid & 63, quad = lane >> 4, l16 = lane & 15;
    const int m0 = blockIdx.x * 64;
    const int n0 = wave * 64;

    // stage A tile (reg round-trip; once per block, amortized over K-loop)
#pragma unroll
    for (int r = 0; r < ROUNDS; ++r) {
        int c = tid + r * NTHR;
        int row = c / CPR, ko = (c % CPR) * 8;
        int grow = m0 + row;
        if (grow >= M) grow = M - 1;
        v8s v = *(const v8s*)(A + (size_t)grow * lda + ko);
        *(v8s*)&aT[row * LDK + ko] = v;
    }
    __syncthreads();

    const unsigned short* Bp[4];
#pragma unroll
    for (int ni = 0; ni < 4; ++ni)
        Bp[ni] = WT + (size_t)(n0 + ni * 16 + l16) * K + quad * 8;

    v4f acc[4][4];
#pragma unroll
    for (int mi = 0; mi < 4; ++mi)
#pragma unroll
        for (int ni = 0; ni < 4; ++ni) acc[mi][ni] = (v4f){0.f, 0.f, 0.f, 0.f};

#pragma unroll 4
    for (int j = 0; j < K32; ++j) {
        v8s a[4], b[4];
#pragma unroll
        for (int ni = 0; ni < 4; ++ni) b[ni] = *(const v8s*)(Bp[ni] + j * 32);
#pragma unroll
        for (int mi = 0; mi < 4; ++mi)
            a[mi] = *(const v8s*)&aT[(mi * 16 + l16) * LDK + j * 32 + quad * 8];
#pragma unroll
        for (int mi = 0; mi < 4; ++mi)
#pragma unroll
            for (int ni = 0; ni < 4; ++ni)
                acc[mi][ni] = __builtin_amdgcn_mfma_f32_16x16x32_bf16(a[mi], b[ni],
                                                                      acc[mi][ni], 0, 0, 0);
    }

    int fin = is_final ? *modep : 0;
#pragma unroll
    for (int ni = 0; ni < 4; ++ni) {
        int colc = n0 + ni * 16 + l16;
        float bv = b2f(bias[colc]);
#pragma unroll
        for (int mi = 0; mi < 4; ++mi) {
#pragma unroll
            for (int r = 0; r < 4; ++r) {
                int row = m0 + mi * 16 + quad * 4 + r;
                if (row < M) {
                    float v = acc[mi][ni][r] + bv;
                    if (dotanh) v = tanhf(v);
                    if (fin) ((float*)out)[(size_t)row * ldo + colc] = v;
                    else     ((unsigned short*)out)[(size_t)row * ldo + colc] = f2b(v);
                }
            }
        }
    }
}

static inline size_t al256(size_t x) { return (x + 255) & ~(size_t)255; }

extern "C" void kernel_launch(void* const* d_in, const int* in_sizes, int n_in,
                              void* d_out, int out_size, void* d_ws, size_t ws_size,
                              hipStream_t stream) {
    const void* x  = d_in[0];
    const int* src = (const int*)d_in[1];
    const int* dst = (const int*)d_in[2];
    const void* W1 = d_in[3]; const void* b1 = d_in[4];
    const void* W2 = d_in[5]; const void* b2 = d_in[6];
    const void* W3 = d_in[7]; const void* b3 = d_in[8];
    const int E = in_sizes[1];

    // workspace carve-up (~58.6 MB)
    char* p = (char*)d_ws;
    int* mode     = (int*)p;            p += 256;
    int* cnt      = (int*)p;            p += al256((size_t)NN * 4);
    float* dinv   = (float*)p;          p += al256((size_t)NN * 4);
    unsigned short* ell = (unsigned short*)p; p += al256((size_t)NN * CAP * 2);
    unsigned short* WT1 = (unsigned short*)p; p += al256((size_t)256 * 256 * 2);
    unsigned short* WT2 = (unsigned short*)p; p += al256((size_t)256 * 512 * 2);
    unsigned short* WT3 = (unsigned short*)p; p += al256((size_t)128 * 512 * 2);
    unsigned short* bb1 = (unsigned short*)p; p += al256((size_t)256 * 2);
    unsigned short* bb2 = (unsigned short*)p; p += al256((size_t)256 * 2);
    unsigned short* bb3 = (unsigned short*)p; p += al256((size_t)128 * 2);
    unsigned short* buf = (unsigned short*)p; p += al256((size_t)NN * 512 * 2);

    hipMemsetAsync(cnt, 0, (size_t)NN * 4, stream);
    sniff_kernel<<<1, 64, 0, stream>>>((const unsigned short*)x, mode);
    prep_kernel<<<4150, 256, 0, stream>>>(x, W1, W2, W3, b1, b2, b3,
                                          buf, WT1, WT2, WT3, bb1, bb2, bb3, mode);
    int eb = (E + 255) / 256;
    fill_kernel<<<eb, 256, 0, stream>>>(src, dst, cnt, ell, E);
    dinv_kernel<<<(NN + 255) / 256, 256, 0, stream>>>(cnt, dinv, NN);

    const int SPMM_GRID = NN / 4;          // 4 waves (nodes) per 256-thread block
    const int GB = (NN + 63) / 64;         // 782 gemm row-blocks

    // L1: buf = [x(0:128) | x1(128:256)]; gemm K=256 in-place -> cols 0:256
    spmm_kernel<2><<<SPMM_GRID, 256, 0, stream>>>(buf, 512, cnt, ell, dinv, buf + 128, 512);
    gemm_kernel<8, 4><<<GB, 256, 0, stream>>>(buf, 512, WT1, bb1, buf, 512, NN, 1, 0, mode);
    // L2..L4: x1 into cols 256:512, gemm K=512 in-place -> cols 0:256
    spmm_kernel<4><<<SPMM_GRID, 256, 0, stream>>>(buf, 512, cnt, ell, dinv, buf + 256, 512);
    gemm_kernel<16, 4><<<GB, 256, 0, stream>>>(buf, 512, WT2, bb2, buf, 512, NN, 1, 0, mode);
    spmm_kernel<4><<<SPMM_GRID, 256, 0, stream>>>(buf, 512, cnt, ell, dinv, buf + 256, 512);
    gemm_kernel<16, 4><<<GB, 256, 0, stream>>>(buf, 512, WT2, bb2, buf, 512, NN, 1, 0, mode);
    spmm_kernel<4><<<SPMM_GRID, 256, 0, stream>>>(buf, 512, cnt, ell, dinv, buf + 256, 512);
    gemm_kernel<16, 4><<<GB, 256, 0, stream>>>(buf, 512, WT2, bb2, buf, 512, NN, 1, 0, mode);
    // L5 (no tanh) -> d_out (50000 x 128, bf16 or fp32 per mode)
    spmm_kernel<4><<<SPMM_GRID, 256, 0, stream>>>(buf, 512, cnt, ell, dinv, buf + 256, 512);
    gemm_kernel<16, 2><<<GB, 128, 0, stream>>>(buf, 512, WT3, bb3, d_out, 128, NN, 0, 1, mode);
}